// Round 4
// baseline (36.545 us; speedup 1.0000x reference)
//
#include <hip/hip_runtime.h>

// MMD loss: mean(delta @ delta.T) == ||colsum(source - target)||^2 / N^2.
// O(N*D) streaming reduction (67 MB read).
// R3 lessons: atomic write-through (16 B/atomic to HBM) + zero_ws launch +
// 16-waves/CU occupancy were the remaining costs. This version:
//  - 512 blocks x 1024 threads (2 blocks/CU -> 32 waves/CU, max occupancy)
//  - NO atomics: each block stores its own 1024-float partial slice
//    (pure coalesced stores, no zero_ws kernel needed)
//  - finish: one 1024-thread block folds 512x1024 partials (2 MB, coalesced)
// Fallback to the proven atomic path if ws_size < 2 MB.

#define MMD_N 8192
#define MMD_D 1024

// ---------------- primary path: partial-store, 2 kernels ----------------
#define CS_BLOCKS 512
#define CS_THREADS 1024
#define TEAMS 4
#define ROWS_PER_BLOCK (MMD_N / CS_BLOCKS)        // 16
#define ROWS_PER_TEAM (ROWS_PER_BLOCK / TEAMS)    // 4

__global__ __launch_bounds__(CS_THREADS) void mmd_colsum_store(
    const float* __restrict__ src, const float* __restrict__ tgt,
    float* __restrict__ ws) {
    const int tid  = threadIdx.x;
    const int team = tid >> 8;    // 0..3
    const int col4 = tid & 255;   // float4 column
    const int row0 = blockIdx.x * ROWS_PER_BLOCK + team * ROWS_PER_TEAM;
    const float4* s4 = reinterpret_cast<const float4*>(src);
    const float4* t4 = reinterpret_cast<const float4*>(tgt);

    float4 s[ROWS_PER_TEAM], t[ROWS_PER_TEAM];
#pragma unroll
    for (int r = 0; r < ROWS_PER_TEAM; ++r) {
        const int idx = (row0 + r) * (MMD_D / 4) + col4;
        s[r] = s4[idx];
        t[r] = t4[idx];
    }
    float4 acc = make_float4(0.f, 0.f, 0.f, 0.f);
#pragma unroll
    for (int r = 0; r < ROWS_PER_TEAM; ++r) {
        acc.x += s[r].x - t[r].x;
        acc.y += s[r].y - t[r].y;
        acc.z += s[r].z - t[r].z;
        acc.w += s[r].w - t[r].w;
    }

    __shared__ float4 red[TEAMS][256];
    red[team][col4] = acc;
    __syncthreads();
    if (tid < 256) {
        float4 a = red[0][tid];
        float4 b = red[1][tid];
        float4 c = red[2][tid];
        float4 d = red[3][tid];
        float4 tot;
        tot.x = (a.x + b.x) + (c.x + d.x);
        tot.y = (a.y + b.y) + (c.y + d.y);
        tot.z = (a.z + b.z) + (c.z + d.z);
        tot.w = (a.w + b.w) + (c.w + d.w);
        reinterpret_cast<float4*>(ws)[blockIdx.x * 256 + tid] = tot;
    }
}

__global__ __launch_bounds__(1024) void mmd_finish_store(
    const float* __restrict__ ws, float* __restrict__ out) {
    const int tid  = threadIdx.x;
    const int team = tid >> 8;    // 0..3: each team folds 128 partial rows
    const int c    = tid & 255;
    const float4* w4 = reinterpret_cast<const float4*>(ws);
    float4 acc = make_float4(0.f, 0.f, 0.f, 0.f);
#pragma unroll 8
    for (int r = team * (CS_BLOCKS / TEAMS); r < (team + 1) * (CS_BLOCKS / TEAMS); ++r) {
        float4 v = w4[r * 256 + c];
        acc.x += v.x; acc.y += v.y; acc.z += v.z; acc.w += v.w;
    }
    __shared__ float4 red[TEAMS][256];
    red[team][c] = acc;
    __syncthreads();

    float sq = 0.f;
    if (tid < 256) {
        float4 a = red[0][tid];
        float4 b = red[1][tid];
        float4 cc = red[2][tid];
        float4 d = red[3][tid];
        float4 tot;
        tot.x = (a.x + b.x) + (cc.x + d.x);
        tot.y = (a.y + b.y) + (cc.y + d.y);
        tot.z = (a.z + b.z) + (cc.z + d.z);
        tot.w = (a.w + b.w) + (cc.w + d.w);
        sq = tot.x * tot.x + tot.y * tot.y + tot.z * tot.z + tot.w * tot.w;
    }
    // reduce sq over threads 0..255 (waves 0..3)
    for (int off = 32; off > 0; off >>= 1)
        sq += __shfl_down(sq, off, 64);
    __shared__ float part[4];
    if (tid < 256 && (tid & 63) == 0) part[tid >> 6] = sq;
    __syncthreads();
    if (tid == 0) {
        float totsq = part[0] + part[1] + part[2] + part[3];
        out[0] = totsq / ((float)MMD_N * (float)MMD_N);
    }
}

// ---------------- fallback path (ws < 2 MB): proven R3 atomic version ----
#define NREP 16
#define FB_BLOCKS 256
#define FB_ROWS_PER_TEAM 8

__global__ __launch_bounds__(256) void mmd_zero_ws(float* __restrict__ ws) {
    float4* w4 = reinterpret_cast<float4*>(ws);
#pragma unroll
    for (int i = 0; i < NREP; ++i)
        w4[i * 256 + threadIdx.x] = make_float4(0.f, 0.f, 0.f, 0.f);
}

__global__ __launch_bounds__(1024) void mmd_colsum_atomic(
    const float* __restrict__ src, const float* __restrict__ tgt,
    float* __restrict__ ws) {
    const int tid  = threadIdx.x;
    const int team = tid >> 8;
    const int col4 = tid & 255;
    const int row0 = blockIdx.x * (TEAMS * FB_ROWS_PER_TEAM) + team * FB_ROWS_PER_TEAM;
    const float4* s4 = reinterpret_cast<const float4*>(src);
    const float4* t4 = reinterpret_cast<const float4*>(tgt);

    float4 acc = make_float4(0.f, 0.f, 0.f, 0.f);
#pragma unroll
    for (int r = 0; r < FB_ROWS_PER_TEAM; ++r) {
        const int idx = (row0 + r) * (MMD_D / 4) + col4;
        float4 s = s4[idx];
        float4 t = t4[idx];
        acc.x += s.x - t.x;
        acc.y += s.y - t.y;
        acc.z += s.z - t.z;
        acc.w += s.w - t.w;
    }
    __shared__ float4 red[TEAMS][256];
    red[team][col4] = acc;
    __syncthreads();
    if (tid < 256) {
        float4 a = red[0][tid];
        float4 b = red[1][tid];
        float4 c = red[2][tid];
        float4 d = red[3][tid];
        float4 tot;
        tot.x = (a.x + b.x) + (c.x + d.x);
        tot.y = (a.y + b.y) + (c.y + d.y);
        tot.z = (a.z + b.z) + (c.z + d.z);
        tot.w = (a.w + b.w) + (c.w + d.w);
        float* wrep = ws + (blockIdx.x & (NREP - 1)) * MMD_D;
        atomicAdd(&wrep[4 * tid + 0], tot.x);
        atomicAdd(&wrep[4 * tid + 1], tot.y);
        atomicAdd(&wrep[4 * tid + 2], tot.z);
        atomicAdd(&wrep[4 * tid + 3], tot.w);
    }
}

__global__ __launch_bounds__(256) void mmd_finish_atomic(
    const float* __restrict__ ws, float* __restrict__ out) {
    const int tid = threadIdx.x;
    const float4* w4 = reinterpret_cast<const float4*>(ws);
    float4 tot = make_float4(0.f, 0.f, 0.f, 0.f);
#pragma unroll
    for (int i = 0; i < NREP; ++i) {
        float4 v = w4[i * 256 + tid];
        tot.x += v.x; tot.y += v.y; tot.z += v.z; tot.w += v.w;
    }
    float sq = tot.x * tot.x + tot.y * tot.y + tot.z * tot.z + tot.w * tot.w;
    for (int off = 32; off > 0; off >>= 1)
        sq += __shfl_down(sq, off, 64);
    __shared__ float part[4];
    if ((tid & 63) == 0) part[tid >> 6] = sq;
    __syncthreads();
    if (tid == 0) {
        float totsq = part[0] + part[1] + part[2] + part[3];
        out[0] = totsq / ((float)MMD_N * (float)MMD_N);
    }
}

extern "C" void kernel_launch(void* const* d_in, const int* in_sizes, int n_in,
                              void* d_out, int out_size, void* d_ws, size_t ws_size,
                              hipStream_t stream) {
    const float* src = (const float*)d_in[0];
    const float* tgt = (const float*)d_in[1];
    float* out = (float*)d_out;
    float* ws = (float*)d_ws;

    if (ws_size >= (size_t)CS_BLOCKS * MMD_D * sizeof(float)) {
        // primary: 2 kernels, no atomics, no zeroing
        mmd_colsum_store<<<CS_BLOCKS, CS_THREADS, 0, stream>>>(src, tgt, ws);
        mmd_finish_store<<<1, 1024, 0, stream>>>(ws, out);
    } else {
        mmd_zero_ws<<<1, 256, 0, stream>>>(ws);
        mmd_colsum_atomic<<<FB_BLOCKS, 1024, 0, stream>>>(src, tgt, ws);
        mmd_finish_atomic<<<1, 256, 0, stream>>>(ws, out);
    }
}

// Round 5
// 25.547 us; speedup vs baseline: 1.4305x; 1.4305x over previous
//
#include <hip/hip_runtime.h>

// MMD loss: mean(delta @ delta.T) == ||colsum(source - target)||^2 / N^2.
// O(N*D) streaming reduction (67 MB read).
// R4 lesson: a single-block fold of 2 MB runs at one CU's L2 rate (~15 us) --
// the final reduction must be partitioned by COLUMN across many blocks
// (each column needs ALL slices before squaring).
// R2/R4 lesson: 8-loads-then-die threads underperform; keep R3's load shape
// (256 blocks x 1024 thr, 16 float4 loads/thread, 16 waves/CU).
// This version: colsum stores one slice per block (no atomics, no zeroing);
// finale = 64 blocks, column-partitioned, shfl-reduce, 256 atomicAdds into
// memset-zeroed d_out.

#define MMD_N 8192
#define MMD_D 1024
#define CS_BLOCKS 256
#define CS_THREADS 1024
#define TEAMS 4
#define ROWS_PER_TEAM 8   // TEAMS * ROWS_PER_TEAM * CS_BLOCKS == MMD_N
#define INV_N2 1.4901161193847656e-8f  // 1 / 8192^2

__global__ __launch_bounds__(CS_THREADS) void mmd_colsum(
    const float* __restrict__ src, const float* __restrict__ tgt,
    float* __restrict__ ws) {
    const int tid  = threadIdx.x;
    const int team = tid >> 8;    // 0..3
    const int col4 = tid & 255;   // float4 column
    const int row0 = blockIdx.x * (TEAMS * ROWS_PER_TEAM) + team * ROWS_PER_TEAM;
    const float4* s4 = reinterpret_cast<const float4*>(src);
    const float4* t4 = reinterpret_cast<const float4*>(tgt);

    float4 acc = make_float4(0.f, 0.f, 0.f, 0.f);
#pragma unroll
    for (int r = 0; r < ROWS_PER_TEAM; ++r) {
        const int idx = (row0 + r) * (MMD_D / 4) + col4;
        float4 s = s4[idx];
        float4 t = t4[idx];
        acc.x += s.x - t.x;
        acc.y += s.y - t.y;
        acc.z += s.z - t.z;
        acc.w += s.w - t.w;
    }

    // cross-team fold in LDS: 4 teams x 256 float4 = 16 KiB
    __shared__ float4 red[TEAMS][256];
    red[team][col4] = acc;
    __syncthreads();
    if (tid < 256) {
        float4 a = red[0][tid];
        float4 b = red[1][tid];
        float4 c = red[2][tid];
        float4 d = red[3][tid];
        float4 tot;
        tot.x = (a.x + b.x) + (c.x + d.x);
        tot.y = (a.y + b.y) + (c.y + d.y);
        tot.z = (a.z + b.z) + (c.z + d.z);
        tot.w = (a.w + b.w) + (c.w + d.w);
        // coalesced slice store: block bid owns ws[bid*1024 .. +1023]
        reinterpret_cast<float4*>(ws)[blockIdx.x * 256 + tid] = tot;
    }
}

// 64 blocks x 256 threads. Wave j (=tid>>6) of block b owns float4-column
// c = 4b + j; it reads that column across ALL 256 slices (full column sum
// before squaring), shfl-reduces, squares, one atomicAdd per wave.
__global__ __launch_bounds__(256) void mmd_finale(
    const float* __restrict__ ws, float* __restrict__ out) {
    const int tid  = threadIdx.x;
    const int j    = tid >> 6;   // wave id 0..3
    const int lane = tid & 63;
    const int c    = blockIdx.x * 4 + j;  // float4 column index 0..255
    const float4* w4 = reinterpret_cast<const float4*>(ws);

    float4 acc = make_float4(0.f, 0.f, 0.f, 0.f);
#pragma unroll
    for (int k = 0; k < CS_BLOCKS / 64; ++k) {  // 4 slices per lane
        float4 v = w4[(lane + 64 * k) * 256 + c];
        acc.x += v.x; acc.y += v.y; acc.z += v.z; acc.w += v.w;
    }
    // wave64 reduce each component -> lane 0 holds full column sums
    for (int off = 32; off > 0; off >>= 1) {
        acc.x += __shfl_down(acc.x, off, 64);
        acc.y += __shfl_down(acc.y, off, 64);
        acc.z += __shfl_down(acc.z, off, 64);
        acc.w += __shfl_down(acc.w, off, 64);
    }
    if (lane == 0) {
        float sq = acc.x * acc.x + acc.y * acc.y + acc.z * acc.z + acc.w * acc.w;
        atomicAdd(out, sq * INV_N2);
    }
}

extern "C" void kernel_launch(void* const* d_in, const int* in_sizes, int n_in,
                              void* d_out, int out_size, void* d_ws, size_t ws_size,
                              hipStream_t stream) {
    const float* src = (const float*)d_in[0];
    const float* tgt = (const float*)d_in[1];
    float* out = (float*)d_out;
    float* ws = (float*)d_ws;  // needs CS_BLOCKS * MMD_D floats = 1 MiB

    hipMemsetAsync(out, 0, sizeof(float), stream);
    mmd_colsum<<<CS_BLOCKS, CS_THREADS, 0, stream>>>(src, tgt, ws);
    mmd_finale<<<64, 256, 0, stream>>>(ws, out);
}

// Round 6
// 21.098 us; speedup vs baseline: 1.7322x; 1.2109x over previous
//
#include <hip/hip_runtime.h>

// MMD loss: mean(delta @ delta.T) == ||colsum(source - target)||^2 / N^2.
// O(N*D) streaming reduction (67 MB read).
// R5 state: colsum ~16us (4.2 TB/s) at 16 waves/CU; fill kernels prove the
// chip streams at 6.8 TB/s. Theory: occupancy x pipeline-depth. This version:
//  - 512 blocks x 512 threads (8 waves/block, ~80 VGPR -> 3 blocks/CU
//    = 24 waves/CU) with all 16 float4 loads issued before any use
//  - loads grouped s[0..7] then t[0..7] for longer per-stream bursts
//  - 2 graph nodes only: colsum block 0 zeroes out[0] (no memset node);
//    finale is column-partitioned across 64 blocks + 256 atomicAdds.

#define MMD_N 8192
#define MMD_D 1024
#define CS_BLOCKS 512
#define CS_THREADS 512
#define TEAMS 2
#define ROWS_PER_TEAM 8   // CS_BLOCKS * TEAMS * ROWS_PER_TEAM == MMD_N
#define INV_N2 1.4901161193847656e-8f  // 1 / 8192^2

__global__ __launch_bounds__(CS_THREADS) void mmd_colsum(
    const float* __restrict__ src, const float* __restrict__ tgt,
    float* __restrict__ ws, float* __restrict__ out) {
    const int tid  = threadIdx.x;
    const int team = tid >> 8;    // 0..1
    const int col4 = tid & 255;   // float4 column
    const int row0 = blockIdx.x * (TEAMS * ROWS_PER_TEAM) + team * ROWS_PER_TEAM;
    const float4* s4 = reinterpret_cast<const float4*>(src);
    const float4* t4 = reinterpret_cast<const float4*>(tgt);

    if (blockIdx.x == 0 && tid == 0) out[0] = 0.f;  // replaces memset node

    // Issue all 16 loads before any consumption: 8 from src, then 8 from tgt
    // (longer sequential bursts per HBM stream).
    float4 s[ROWS_PER_TEAM], t[ROWS_PER_TEAM];
#pragma unroll
    for (int r = 0; r < ROWS_PER_TEAM; ++r)
        s[r] = s4[(row0 + r) * (MMD_D / 4) + col4];
#pragma unroll
    for (int r = 0; r < ROWS_PER_TEAM; ++r)
        t[r] = t4[(row0 + r) * (MMD_D / 4) + col4];

    float4 acc = make_float4(0.f, 0.f, 0.f, 0.f);
#pragma unroll
    for (int r = 0; r < ROWS_PER_TEAM; ++r) {
        acc.x += s[r].x - t[r].x;
        acc.y += s[r].y - t[r].y;
        acc.z += s[r].z - t[r].z;
        acc.w += s[r].w - t[r].w;
    }

    // cross-team fold in LDS: 2 teams x 256 float4 = 8 KiB
    __shared__ float4 red[TEAMS][256];
    red[team][col4] = acc;
    __syncthreads();
    if (tid < 256) {
        float4 a = red[0][tid];
        float4 b = red[1][tid];
        float4 tot;
        tot.x = a.x + b.x;
        tot.y = a.y + b.y;
        tot.z = a.z + b.z;
        tot.w = a.w + b.w;
        // coalesced slice store: block bid owns ws[bid*1024 .. +1023]
        reinterpret_cast<float4*>(ws)[blockIdx.x * 256 + tid] = tot;
    }
}

// 64 blocks x 256 threads. Wave j of block b owns float4-column c = 4b + j;
// lanes split the 512 slices (8 each), shfl-reduce, square, one atomicAdd
// per wave (256 total).
__global__ __launch_bounds__(256) void mmd_finale(
    const float* __restrict__ ws, float* __restrict__ out) {
    const int tid  = threadIdx.x;
    const int j    = tid >> 6;   // wave id 0..3
    const int lane = tid & 63;
    const int c    = blockIdx.x * 4 + j;  // float4 column index 0..255
    const float4* w4 = reinterpret_cast<const float4*>(ws);

    float4 acc = make_float4(0.f, 0.f, 0.f, 0.f);
#pragma unroll
    for (int k = 0; k < CS_BLOCKS / 64; ++k) {  // 8 slices per lane
        float4 v = w4[(lane + 64 * k) * 256 + c];
        acc.x += v.x; acc.y += v.y; acc.z += v.z; acc.w += v.w;
    }
    for (int off = 32; off > 0; off >>= 1) {
        acc.x += __shfl_down(acc.x, off, 64);
        acc.y += __shfl_down(acc.y, off, 64);
        acc.z += __shfl_down(acc.z, off, 64);
        acc.w += __shfl_down(acc.w, off, 64);
    }
    if (lane == 0) {
        float sq = acc.x * acc.x + acc.y * acc.y + acc.z * acc.z + acc.w * acc.w;
        atomicAdd(out, sq * INV_N2);
    }
}

extern "C" void kernel_launch(void* const* d_in, const int* in_sizes, int n_in,
                              void* d_out, int out_size, void* d_ws, size_t ws_size,
                              hipStream_t stream) {
    const float* src = (const float*)d_in[0];
    const float* tgt = (const float*)d_in[1];
    float* out = (float*)d_out;
    float* ws = (float*)d_ws;  // needs CS_BLOCKS * MMD_D floats = 2 MiB

    mmd_colsum<<<CS_BLOCKS, CS_THREADS, 0, stream>>>(src, tgt, ws, out);
    mmd_finale<<<64, 256, 0, stream>>>(ws, out);
}